// Round 12
// baseline (182.770 us; speedup 1.0000x reference)
//
#include <hip/hip_runtime.h>
#include <math.h>

#define B_  16
#define L_  4096
#define D_  64
#define R_  4
#define NB_ 64
#define BL_ 64
#define FIXCAP 8192

typedef _Float16 f16x8 __attribute__((ext_vector_type(8)));
typedef _Float16 f16x2 __attribute__((ext_vector_type(2)));
typedef float    f32x4 __attribute__((ext_vector_type(4)));

// ---------------- ws layout ----------------
// [0MB,1MB)     rmn    double   [B][R][32][64]
// [1MB,2MB)     h      int      [B][R][L]
// [2MB,3MB)     hi     int      [B][R][L]
// [3MB,4MB)     oi     int      [B][R][L]
// [4MB,5MB)     lse    float    [B][R][L]   (original index)
// [5MB,+256)    rwmax float[64]; [+256,+512) rwsum; [+512] fix_cnt; [+1024,) fix_list
// [6MB,40MB)    attn   _Float16 [B][L][R][64]
// [40MB,+256K)  rhi    _Float16 [B][128][64]
// [40.5MB,+256K)rlo    _Float16 [B][128][64]
// [41MB,45MB)   meta   int4     [B*R][L]
// [45MB,53MB)   qhf    _Float16 [B][L][64]
// [53MB,61MB)   khf    _Float16 [B][L][64]
// [61MB,69MB)   vhf    _Float16 [B][L][64]

// K0: normalize rand_matrix along d, store fp64 + split-f16 copies; zero fix_cnt.
__global__ __launch_bounds__(64) void k_rmnorm(const float* __restrict__ rm,
                                               double* __restrict__ rmn,
                                               _Float16* __restrict__ rhi_g,
                                               _Float16* __restrict__ rlo_g,
                                               int* __restrict__ fix_cnt) {
    if (blockIdx.x == 0 && threadIdx.x == 0) *fix_cnt = 0;
    int blk = blockIdx.x;                 // b*128 + r*32 + n
    int b = blk >> 7, r = (blk >> 5) & 3, n = blk & 31;
    int d = threadIdx.x;
    double v = (double)rm[(((size_t)b * 64 + d) * 4 + r) * 32 + n];
    double sq = v * v;
    #pragma unroll
    for (int off = 32; off > 0; off >>= 1) sq += __shfl_down(sq, off);
    double tot = __shfl(sq, 0);
    double nv = v / sqrt(tot);
    rmn[(((size_t)b * 4 + r) * 32 + n) * 64 + d] = nv;
    float f = (float)nv;
    _Float16 hi = (_Float16)f;
    size_t gi = ((size_t)b * 128 + r * 32 + n) * 64 + d;
    rhi_g[gi] = hi;
    rlo_g[gi] = (_Float16)(f - (float)hi);
}

// K0b: streaming f16 prep (qhf raw, khf scaled, vhf). No LDS -> high occupancy.
__global__ __launch_bounds__(256) void k_prep(const float* __restrict__ q,
                                              const float* __restrict__ value,
                                              _Float16* __restrict__ qhf,
                                              _Float16* __restrict__ khf,
                                              _Float16* __restrict__ vhf) {
    int xcd = blockIdx.x & 7, slot = blockIdx.x >> 3;   // 128 slots
    int b = xcd * 2 + (slot >> 6), chunk = slot & 63;
    int t = threadIdx.x;
    int row = chunk * 64 + (t >> 2), sub = t & 3;       // 4 threads/row, 16 d each
    size_t off = ((size_t)(b * L_ + row)) * 64 + sub * 16;

    const float4* qp = (const float4*)(q + off);
    float qv[16];
    #pragma unroll
    for (int c = 0; c < 4; c++) {
        float4 tt = qp[c];
        qv[4*c+0]=tt.x; qv[4*c+1]=tt.y; qv[4*c+2]=tt.z; qv[4*c+3]=tt.w;
    }
    float ss = 0.f;
    #pragma unroll
    for (int j = 0; j < 16; j++) ss += qv[j] * qv[j];
    ss += __shfl_xor(ss, 1);
    ss += __shfl_xor(ss, 2);
    float nr = sqrtf(ss); if (nr < 1e-12f) nr = 1e-12f;
    float kscale = 0.125f / nr;
    f16x8 qh0, qh1, kh0, kh1;
    #pragma unroll
    for (int j = 0; j < 8; j++) {
        qh0[j] = (_Float16)qv[j];            qh1[j] = (_Float16)qv[8+j];
        kh0[j] = (_Float16)(qv[j] * kscale); kh1[j] = (_Float16)(qv[8+j] * kscale);
    }
    *(f16x8*)(qhf + off) = qh0; *(f16x8*)(qhf + off + 8) = qh1;
    *(f16x8*)(khf + off) = kh0; *(f16x8*)(khf + off + 8) = kh1;

    const float4* vp = (const float4*)(value + off);
    float vv[16];
    #pragma unroll
    for (int c = 0; c < 4; c++) {
        float4 tt = vp[c];
        vv[4*c+0]=tt.x; vv[4*c+1]=tt.y; vv[4*c+2]=tt.z; vv[4*c+3]=tt.w;
    }
    f16x8 vh0, vh1;
    #pragma unroll
    for (int j = 0; j < 8; j++) { vh0[j]=(_Float16)vv[j]; vh1[j]=(_Float16)vv[8+j]; }
    *(f16x8*)(vhf + off) = vh0; *(f16x8*)(vhf + off + 8) = vh1;
}

// K1: split-f16 MFMA hash (hash only now); XCD-pinned b.
__global__ __launch_bounds__(256, 4) void k_hash(const float* __restrict__ q,
                                                 const _Float16* __restrict__ rhi_g,
                                                 const _Float16* __restrict__ rlo_g,
                                                 int* __restrict__ h_ws,
                                                 int* __restrict__ fix_cnt,
                                                 int* __restrict__ fix_list) {
    __shared__ __align__(16) char smem[36864];
    _Float16* Rhi = (_Float16*)smem;            // [128][72]
    _Float16* Rlo = (_Float16*)(smem + 18432);  // [128][72]
    float*    Sc  = (float*)smem;               // overlay [64][133]

    int xcd = blockIdx.x & 7, slot = blockIdx.x >> 3;   // 128 slots
    int b = xcd * 2 + (slot >> 6), chunk = slot & 63;
    int tid = threadIdx.x;
    int w = tid >> 6, lane = tid & 63, quad = lane >> 4, l15 = lane & 15;

    {   // stage R split halves
        int row = tid >> 1, dh = (tid & 1) * 32;
        const _Float16* sh = rhi_g + ((size_t)b * 128 + row) * 64 + dh;
        const _Float16* sl = rlo_g + ((size_t)b * 128 + row) * 64 + dh;
        #pragma unroll
        for (int g = 0; g < 4; g++) {
            *(f16x8*)&Rhi[row * 72 + dh + g * 8] = *(const f16x8*)(sh + g * 8);
            *(f16x8*)&Rlo[row * 72 + dh + g * 8] = *(const f16x8*)(sl + g * 8);
        }
    }

    int qrow = chunk * 64 + w * 16 + l15;
    const float* qp = q + ((size_t)(b * L_ + qrow)) * 64;
    f16x8 Ahi[2], Alo[2];
    #pragma unroll
    for (int kt = 0; kt < 2; kt++) {
        float4 t0 = *(const float4*)(qp + kt * 32 + quad * 8);
        float4 t1 = *(const float4*)(qp + kt * 32 + quad * 8 + 4);
        float fv[8] = {t0.x, t0.y, t0.z, t0.w, t1.x, t1.y, t1.z, t1.w};
        #pragma unroll
        for (int j = 0; j < 8; j++) {
            _Float16 hi = (_Float16)fv[j];
            Ahi[kt][j] = hi;
            Alo[kt][j] = (_Float16)(fv[j] - (float)hi);
        }
    }
    __syncthreads();

    f32x4 acc[8];
    #pragma unroll
    for (int jt = 0; jt < 8; jt++) acc[jt] = (f32x4){0.f, 0.f, 0.f, 0.f};
    #pragma unroll
    for (int jt = 0; jt < 8; jt++) {
        #pragma unroll
        for (int kt = 0; kt < 2; kt++) {
            f16x8 bh = *(const f16x8*)&Rhi[(jt * 16 + l15) * 72 + kt * 32 + quad * 8];
            f16x8 bl = *(const f16x8*)&Rlo[(jt * 16 + l15) * 72 + kt * 32 + quad * 8];
            acc[jt] = __builtin_amdgcn_mfma_f32_16x16x32_f16(Ahi[kt], bh, acc[jt], 0, 0, 0);
            acc[jt] = __builtin_amdgcn_mfma_f32_16x16x32_f16(Ahi[kt], bl, acc[jt], 0, 0, 0);
            acc[jt] = __builtin_amdgcn_mfma_f32_16x16x32_f16(Alo[kt], bh, acc[jt], 0, 0, 0);
        }
    }
    __syncthreads();

    #pragma unroll
    for (int jt = 0; jt < 8; jt++) {
        #pragma unroll
        for (int reg = 0; reg < 4; reg++)
            Sc[(w * 16 + quad * 4 + reg) * 133 + jt * 16 + l15] = acc[jt][reg];
    }
    __syncthreads();

    {
        int row = tid & 63, r = tid >> 6;
        const float* sp = &Sc[row * 133 + r * 32];
        float bp = -1e30f, bn = -1e30f; int ip = 0, in2 = 0;
        float v1 = -1e30f, v2 = -1e30f;
        #pragma unroll
        for (int n = 0; n < 32; n++) {
            float v = sp[n], nv = -v;
            if (v > bp)  { bp = v;  ip = n; }
            if (nv > bn) { bn = nv; in2 = n; }
            if (v > v1)       { v2 = v1; v1 = v; }
            else if (v > v2)  { v2 = v; }
            if (nv > v1)      { v2 = v1; v1 = nv; }
            else if (nv > v2) { v2 = nv; }
        }
        int i1 = (bp >= bn) ? ip : (32 + in2);
        int l = chunk * 64 + row;
        h_ws[((size_t)(b * 4 + r)) * L_ + l] = i1;
        if (v1 - v2 < 4e-5f) {
            int slot2 = atomicAdd(fix_cnt, 1);
            if (slot2 < FIXCAP) fix_list[slot2] = (b << 14) | (r << 12) | l;
        }
    }
}

// K1b: exact fp64 resolve, one wave per flagged row.
__global__ __launch_bounds__(64) void k_fix(const float* __restrict__ q,
                                            const double* __restrict__ rmn,
                                            const int* __restrict__ fix_cnt,
                                            const int* __restrict__ fix_list,
                                            int* __restrict__ h_ws) {
    int cnt = *fix_cnt; if (cnt > FIXCAP) cnt = FIXCAP;
    int lane = threadIdx.x;
    for (int i = blockIdx.x; i < cnt; i += gridDim.x) {
        int e = fix_list[i];
        int b = e >> 14, r = (e >> 12) & 3, l = e & 4095;
        int n = lane & 31;
        const double* rp = rmn + ((size_t)(b * 4 + r)) * 2048 + n * 64;
        const float* qr = q + ((size_t)(b * L_ + l)) * 64;
        double a0 = 0.0, a1 = 0.0, a2 = 0.0, a3 = 0.0;
        #pragma unroll
        for (int d = 0; d < 64; d += 4) {
            a0 += (double)qr[d]   * rp[d];
            a1 += (double)qr[d+1] * rp[d+1];
            a2 += (double)qr[d+2] * rp[d+2];
            a3 += (double)qr[d+3] * rp[d+3];
        }
        double acc = ((a0 + a1) + (a2 + a3));
        double v = (lane < 32) ? acc : -acc;
        int idx = lane;
        #pragma unroll
        for (int off = 1; off < 64; off <<= 1) {
            double ov = __shfl_xor(v, off);
            int   oidx = __shfl_xor(idx, off);
            if (ov > v || (ov == v && oidx < idx)) { v = ov; idx = oidx; }
        }
        if (lane == 0) h_ws[((size_t)(b * 4 + r)) * L_ + l] = idx;
    }
}

// K2: stable counting sort per (b,r) — 256 threads, 256 sub-chunks of 16.
__global__ __launch_bounds__(256) void k_sort(const int* __restrict__ h_ws,
                                              int* __restrict__ hi_ws,
                                              int* __restrict__ oi_ws) {
    __shared__ unsigned short hs16[4096];
    __shared__ unsigned short cnt[256 * 66];
    __shared__ int partial[4 * 64];
    __shared__ int baseb[64];
    int br = blockIdx.x;
    const int* hp = h_ws + (size_t)br * L_;
    int t = threadIdx.x;
    for (int k = t; k < 4096; k += 256) hs16[k] = (unsigned short)hp[k];
    for (int k = t; k < 256 * 66; k += 256) cnt[k] = 0;
    __syncthreads();
    {
        unsigned short* row = &cnt[t * 66];
        int base = t * 16;
        #pragma unroll
        for (int k = 0; k < 16; k++) row[hs16[base + k]]++;
    }
    __syncthreads();
    {
        int u = t & 63, g = t >> 6;
        int s = 0;
        for (int c = g * 64; c < g * 64 + 64; c++) s += cnt[c * 66 + u];
        partial[g * 64 + u] = s;
    }
    __syncthreads();
    if (t < 64) {
        int tot = partial[t] + partial[64 + t] + partial[128 + t] + partial[192 + t];
        int v = tot;
        #pragma unroll
        for (int off = 1; off < 64; off <<= 1) {
            int u2 = __shfl_up(v, off);
            if (t >= off) v += u2;
        }
        baseb[t] = v - tot;
    }
    __syncthreads();
    {
        int u = t & 63, g = t >> 6;
        int running = baseb[u];
        for (int gg = 0; gg < g; gg++) running += partial[gg * 64 + u];
        for (int c = g * 64; c < g * 64 + 64; c++) {
            int tmp = cnt[c * 66 + u];
            cnt[c * 66 + u] = (unsigned short)running;
            running += tmp;
        }
    }
    __syncthreads();
    {
        int* hi = hi_ws + (size_t)br * L_;
        int* oi = oi_ws + (size_t)br * L_;
        unsigned short* row = &cnt[t * 66];
        int base = t * 16;
        #pragma unroll
        for (int k = 0; k < 16; k++) {
            int idx = base + k;
            int bucket = hs16[idx];
            int pos = row[bucket]++;
            hi[pos] = idx;
            oi[idx] = pos;
        }
    }
}

// K2b: per sorted position meta record
__global__ __launch_bounds__(256) void k_meta(const int* __restrict__ h_ws,
                                              const int* __restrict__ hi_ws,
                                              const int* __restrict__ oi_ws,
                                              int4* __restrict__ meta_ws) {
    int gid = blockIdx.x * 256 + threadIdx.x;
    int br = gid >> 12, spos = gid & 4095;
    int b = br >> 2;
    int p = hi_ws[(size_t)br * L_ + spos];
    int hh = h_ws[(size_t)br * L_ + p];
    int pack = 0, packm1 = 0;
    #pragma unroll
    for (int r2 = 0; r2 < 4; r2++) {
        int bk = oi_ws[((size_t)(b * 4 + r2)) * L_ + p] >> 6;
        pack   |= bk << (8 * r2);
        packm1 |= ((bk + 63) & 63) << (8 * r2);
    }
    meta_ws[(size_t)br * L_ + spos] = make_int4(hh, p, pack, packm1);
}

// K3: MFMA fused attention. Half-batch per dispatch: b = b_base + xcd (one b per
// XCD -> 2 MB working set in 4 MB L2). K staged in LDS; Vt conflict-free;
// Ph overlays Ksh; attn [B][L][R][64].
__global__ __launch_bounds__(256, 4) void k_attn(const _Float16* __restrict__ qhf,
                                                 const _Float16* __restrict__ khf,
                                                 const _Float16* __restrict__ vhf,
                                                 const int4* __restrict__ meta_ws,
                                                 float* __restrict__ lse_ws,
                                                 _Float16* __restrict__ attn_ws,
                                                 int b_base) {
    __shared__ _Float16 Ksh[128 * 76];    // 19456 B; overlaid by Ph[64][136]
    __shared__ _Float16 Vt[64 * 136];     // 17408 B
    __shared__ int4 kmeta[128];

    int xcd = blockIdx.x & 7, slot = blockIdx.x >> 3;   // 256 slots
    int b = b_base + xcd;
    int n = slot >> 2, r = slot & 3;
    int tid = threadIdx.x;
    int w = tid >> 6, lane = tid & 63, quad = lane >> 4, l15 = lane & 15;
    int hibase = (b * 4 + r) * L_;

    if (tid < 128) {
        int nprev = (n + 63) & 63;
        int spos = (tid < 64) ? (nprev * 64 + tid) : (n * 64 + (tid - 64));
        kmeta[tid] = meta_ws[hibase + spos];
    }
    __syncthreads();

    {   // stage K: pure gathered f16 copy, 2 threads per row
        int j = tid >> 1, dh = (tid & 1) * 32;
        const _Float16* src = khf + ((size_t)(b * L_ + kmeta[j].y)) * 64 + dh;
        #pragma unroll
        for (int g = 0; g < 4; g++)
            *(f16x8*)&Ksh[j * 76 + dh + g * 8] = *(const f16x8*)(src + g * 8);
    }
    {   // stage V^T: wave = d-quarter, lane = row-pair -> 2-way bank alias (free)
        int p0 = kmeta[2 * lane].y, p1 = kmeta[2 * lane + 1].y;
        const _Float16* v0 = vhf + ((size_t)(b * L_ + p0)) * 64 + w * 16;
        const _Float16* v1 = vhf + ((size_t)(b * L_ + p1)) * 64 + w * 16;
        f16x8 a00 = *(const f16x8*)v0, a01 = *(const f16x8*)(v0 + 8);
        f16x8 a10 = *(const f16x8*)v1, a11 = *(const f16x8*)(v1 + 8);
        #pragma unroll
        for (int d = 0; d < 8; d++) {
            f16x2 hv = { a00[d], a10[d] };
            *(f16x2*)&Vt[(w * 16 + d) * 136 + 2 * lane] = hv;
            f16x2 hw = { a01[d], a11[d] };
            *(f16x2*)&Vt[(w * 16 + 8 + d) * 136 + 2 * lane] = hw;
        }
    }

    int4 qmw = kmeta[64 + w * 16 + l15];
    const _Float16* qp = qhf + ((size_t)(b * L_ + qmw.y)) * 64;
    f16x8 afr[2];
    afr[0] = *(const f16x8*)(qp + quad * 8);
    afr[1] = *(const f16x8*)(qp + 32 + quad * 8);
    __syncthreads();

    f32x4 acc[8];
    #pragma unroll
    for (int jt = 0; jt < 8; jt++) acc[jt] = (f32x4){0.f, 0.f, 0.f, 0.f};
    #pragma unroll
    for (int jt = 0; jt < 8; jt++) {
        #pragma unroll
        for (int kt = 0; kt < 2; kt++) {
            f16x8 bfr = *(const f16x8*)&Ksh[(jt * 16 + l15) * 76 + kt * 32 + quad * 8];
            acc[jt] = __builtin_amdgcn_mfma_f32_16x16x32_f16(afr[kt], bfr, acc[jt], 0, 0, 0);
        }
    }

    int4 qm4[4], km4[8];
    #pragma unroll
    for (int reg = 0; reg < 4; reg++) qm4[reg] = kmeta[64 + w * 16 + quad * 4 + reg];
    #pragma unroll
    for (int jt = 0; jt < 8; jt++) km4[jt] = kmeta[jt * 16 + l15];
    __syncthreads();                      // QK reads of Ksh done -> overlay

    _Float16* Ph = Ksh;                   // [64][136]
    float lse_r[4];
    #pragma unroll
    for (int reg = 0; reg < 4; reg++) {
        float s[8];
        #pragma unroll
        for (int jt = 0; jt < 8; jt++) {
            float v = acc[jt][reg];
            if (km4[jt].x != qm4[reg].x) v = -1e9f;
            if (qm4[reg].y < km4[jt].y)  v = -1e9f;
            if (qm4[reg].y == km4[jt].y) v = -1e5f;
            s[jt] = v;
        }
        float m = s[0];
        #pragma unroll
        for (int jt = 1; jt < 8; jt++) m = fmaxf(m, s[jt]);
        #pragma unroll
        for (int off = 1; off < 16; off <<= 1) m = fmaxf(m, __shfl_xor(m, off));
        float te[8], sum = 0.f;
        #pragma unroll
        for (int jt = 0; jt < 8; jt++) { te[jt] = __expf(s[jt] - m); sum += te[jt]; }
        #pragma unroll
        for (int off = 1; off < 16; off <<= 1) sum += __shfl_xor(sum, off);
        float inv = __builtin_amdgcn_rcpf(sum);
        lse_r[reg] = m + __logf(sum);
        int i = w * 16 + quad * 4 + reg;
        #pragma unroll
        for (int jt = 0; jt < 8; jt++) {
            int z1 = km4[jt].z ^ qm4[reg].z;
            int z2 = km4[jt].z ^ qm4[reg].w;
            int nz = __popc((z1 + 0x7f7f7f7f) & 0x80808080)
                   + __popc((z2 + 0x7f7f7f7f) & 0x80808080);
            float p = te[jt] * inv * __builtin_amdgcn_rcpf((float)(8 - nz));
            Ph[i * 136 + jt * 16 + l15] = (_Float16)p;
        }
    }
    if (l15 == 0) {
        #pragma unroll
        for (int reg = 0; reg < 4; reg++)
            lse_ws[hibase + qm4[reg].y] = lse_r[reg];
    }
    __syncthreads();                      // Ph complete

    f32x4 oacc[4];
    #pragma unroll
    for (int nt = 0; nt < 4; nt++) oacc[nt] = (f32x4){0.f, 0.f, 0.f, 0.f};
    #pragma unroll
    for (int kt = 0; kt < 4; kt++) {
        f16x8 pa = *(const f16x8*)&Ph[(w * 16 + l15) * 136 + kt * 32 + quad * 8];
        #pragma unroll
        for (int nt = 0; nt < 4; nt++) {
            f16x8 vb = *(const f16x8*)&Vt[(nt * 16 + l15) * 136 + kt * 32 + quad * 8];
            oacc[nt] = __builtin_amdgcn_mfma_f32_16x16x32_f16(pa, vb, oacc[nt], 0, 0, 0);
        }
    }
    #pragma unroll
    for (int reg = 0; reg < 4; reg++) {
        size_t base = (((size_t)(b * L_ + qm4[reg].y)) * 4 + r) * 64;
        #pragma unroll
        for (int nt = 0; nt < 4; nt++)
            attn_ws[base + nt * 16 + l15] = (_Float16)oacc[nt][reg];
    }
}

// K4a: per (b,r) softmax-over-L stats of lse
__global__ __launch_bounds__(256) void k_rw(const float* __restrict__ lse_ws,
                                            float* __restrict__ rwmax,
                                            float* __restrict__ rwsum) {
    __shared__ float  red[256];
    __shared__ double redd[256];
    int br = blockIdx.x;
    const float* lp = lse_ws + (size_t)br * L_;
    int t = threadIdx.x;
    float m = -1e30f;
    for (int k = t; k < L_; k += 256) m = fmaxf(m, lp[k]);
    red[t] = m; __syncthreads();
    for (int s2 = 128; s2 > 0; s2 >>= 1) {
        if (t < s2) red[t] = fmaxf(red[t], red[t + s2]);
        __syncthreads();
    }
    float mm = red[0];
    double s = 0.0;
    for (int k = t; k < L_; k += 256) s += (double)expf(lp[k] - mm);
    redd[t] = s; __syncthreads();
    for (int s2 = 128; s2 > 0; s2 >>= 1) {
        if (t < s2) redd[t] += redd[t + s2];
        __syncthreads();
    }
    if (t == 0) { rwmax[br] = mm; rwsum[br] = (float)redd[0]; }
}

// K4b: combine. XCD-pinned b; attn [B][L][R][64] -> 512 B contiguous per row.
__global__ __launch_bounds__(256) void k_out(const _Float16* __restrict__ attn_ws,
                                             const float* __restrict__ lse_ws,
                                             const float* __restrict__ rwmax,
                                             const float* __restrict__ rwsum,
                                             float* __restrict__ out) {
    int xcd = blockIdx.x & 7, slot = blockIdx.x >> 3;   // 256 slots
    int b = xcd * 2 + (slot >> 7);
    int inner = slot & 127;
    int tid = threadIdx.x;
    int l = inner * 32 + (tid >> 3), g = tid & 7;
    size_t row = (size_t)b * L_ + l;
    float o[8];
    #pragma unroll
    for (int k = 0; k < 8; k++) o[k] = 0.f;
    #pragma unroll
    for (int r = 0; r < 4; r++) {
        int br = b * 4 + r;
        float wgt = __expf(lse_ws[(size_t)br * L_ + l] - rwmax[br])
                  * __builtin_amdgcn_rcpf(rwsum[br]);
        f16x8 av = *(const f16x8*)&attn_ws[(row * 4 + r) * 64 + g * 8];
        #pragma unroll
        for (int k = 0; k < 8; k++) o[k] += (float)av[k] * wgt;
    }
    float4* op = (float4*)(out + row * 64 + g * 8);
    op[0] = make_float4(o[0], o[1], o[2], o[3]);
    op[1] = make_float4(o[4], o[5], o[6], o[7]);
}

extern "C" void kernel_launch(void* const* d_in, const int* in_sizes, int n_in,
                              void* d_out, int out_size, void* d_ws, size_t ws_size,
                              hipStream_t stream) {
    const float* query = (const float*)d_in[0];
    const float* value = (const float*)d_in[1];
    const float* rm    = (const float*)d_in[2];
    char* ws = (char*)d_ws;
    double*    rmn    = (double*)ws;
    int*       h_ws   = (int*)(ws + ((size_t)1 << 20));
    int*       hi_ws  = (int*)(ws + ((size_t)2 << 20));
    int*       oi_ws  = (int*)(ws + ((size_t)3 << 20));
    float*     lse_ws = (float*)(ws + ((size_t)4 << 20));
    float*     rwmax  = (float*)(ws + ((size_t)5 << 20));
    float*     rwsum  = (float*)(ws + ((size_t)5 << 20) + 256);
    int*       fix_cnt= (int*)(ws + ((size_t)5 << 20) + 512);
    int*       fix_list=(int*)(ws + ((size_t)5 << 20) + 1024);
    _Float16*  attn_ws= (_Float16*)(ws + ((size_t)6 << 20));
    _Float16*  rhi_g  = (_Float16*)(ws + ((size_t)40 << 20));
    _Float16*  rlo_g  = (_Float16*)(ws + ((size_t)40 << 20) + ((size_t)1 << 19));
    int4*      meta_ws= (int4*)(ws + ((size_t)41 << 20));
    _Float16*  qhf    = (_Float16*)(ws + ((size_t)45 << 20));
    _Float16*  khf    = (_Float16*)(ws + ((size_t)53 << 20));
    _Float16*  vhf    = (_Float16*)(ws + ((size_t)61 << 20));
    float*     out    = (float*)d_out;

    hipLaunchKernelGGL(k_rmnorm, dim3(2048), dim3(64),  0, stream, rm, rmn, rhi_g, rlo_g, fix_cnt);
    hipLaunchKernelGGL(k_prep,   dim3(1024), dim3(256), 0, stream, query, value, qhf, khf, vhf);
    hipLaunchKernelGGL(k_hash,   dim3(1024), dim3(256), 0, stream, query, rhi_g, rlo_g,
                       h_ws, fix_cnt, fix_list);
    hipLaunchKernelGGL(k_fix,    dim3(64),   dim3(64),  0, stream, query, rmn,
                       fix_cnt, fix_list, h_ws);
    hipLaunchKernelGGL(k_sort,   dim3(64),   dim3(256), 0, stream, h_ws, hi_ws, oi_ws);
    hipLaunchKernelGGL(k_meta,   dim3(1024), dim3(256), 0, stream, h_ws, hi_ws, oi_ws, meta_ws);
    hipLaunchKernelGGL(k_attn,   dim3(2048), dim3(256), 0, stream,
                       qhf, khf, vhf, meta_ws, lse_ws, attn_ws, 0);
    hipLaunchKernelGGL(k_attn,   dim3(2048), dim3(256), 0, stream,
                       qhf, khf, vhf, meta_ws, lse_ws, attn_ws, 8);
    hipLaunchKernelGGL(k_rw,     dim3(64),   dim3(256), 0, stream, lse_ws, rwmax, rwsum);
    hipLaunchKernelGGL(k_out,    dim3(2048), dim3(256), 0, stream,
                       attn_ws, lse_ws, rwmax, rwsum, out);
}

// Round 13
// 175.180 us; speedup vs baseline: 1.0433x; 1.0433x over previous
//
#include <hip/hip_runtime.h>
#include <math.h>

#define B_  16
#define L_  4096
#define D_  64
#define R_  4
#define NB_ 64
#define BL_ 64
#define FIXCAP 8192

typedef _Float16 f16x8 __attribute__((ext_vector_type(8)));
typedef _Float16 f16x2 __attribute__((ext_vector_type(2)));
typedef float    f32x4 __attribute__((ext_vector_type(4)));

// ---------------- ws layout ----------------
// [0MB,1MB)     rmn    double   [B][R][32][64]
// [1MB,2MB)     h      int      [B][R][L]
// [2MB,3MB)     hi     int      [B][R][L]
// [3MB,4MB)     oi     int      [B][R][L]
// [4MB,5MB)     lse    float    [B][R][L]   (original index)
// [5MB,+256)    rwmax float[64]; [+256,+512) rwsum; [+512] fix_cnt; [+1024,) fix_list
// [6MB,40MB)    attn   _Float16 [B][L][R][64]
// [40MB,+256K)  rhi    _Float16 [B][128][64]
// [40.5MB,+256K)rlo    _Float16 [B][128][64]
// [41MB,45MB)   meta   int4     [B*R][L]
// [45MB,53MB)   qhf    _Float16 [B][L][64]
// [53MB,61MB)   khf    _Float16 [B][L][64]
// [61MB,69MB)   vhf    _Float16 [B][L][64]

// K0 (merged): blocks [0,512): rand_matrix normalize (4 waves = 4 (b,r,n) tuples);
// blocks [512,1536): streaming f16 prep (qhf/khf/vhf). Zero fix_cnt.
__global__ __launch_bounds__(256) void k_init(const float* __restrict__ rm,
                                              const float* __restrict__ q,
                                              const float* __restrict__ value,
                                              double* __restrict__ rmn,
                                              _Float16* __restrict__ rhi_g,
                                              _Float16* __restrict__ rlo_g,
                                              _Float16* __restrict__ qhf,
                                              _Float16* __restrict__ khf,
                                              _Float16* __restrict__ vhf,
                                              int* __restrict__ fix_cnt) {
    int tid = threadIdx.x;
    if (blockIdx.x == 0 && tid == 0) *fix_cnt = 0;
    if (blockIdx.x < 512) {               // rmnorm: tuple = blk*4 + wave
        int t4 = blockIdx.x * 4 + (tid >> 6);   // b*128 + r*32 + n
        int b = t4 >> 7, r = (t4 >> 5) & 3, n = t4 & 31;
        int d = tid & 63;
        double v = (double)rm[(((size_t)b * 64 + d) * 4 + r) * 32 + n];
        double sq = v * v;
        #pragma unroll
        for (int off = 32; off > 0; off >>= 1) sq += __shfl_down(sq, off);
        double tot = __shfl(sq, 0);
        double nv = v / sqrt(tot);
        rmn[(((size_t)b * 4 + r) * 32 + n) * 64 + d] = nv;
        float f = (float)nv;
        _Float16 hi = (_Float16)f;
        size_t gi = ((size_t)b * 128 + r * 32 + n) * 64 + d;
        rhi_g[gi] = hi;
        rlo_g[gi] = (_Float16)(f - (float)hi);
        return;
    }
    int blk = blockIdx.x - 512;           // prep: 1024 blocks
    int xcd = blk & 7, slot = blk >> 3;
    int b = xcd * 2 + (slot >> 6), chunk = slot & 63;
    int row = chunk * 64 + (tid >> 2), sub = tid & 3;
    size_t off = ((size_t)(b * L_ + row)) * 64 + sub * 16;

    const float4* qp = (const float4*)(q + off);
    float qv[16];
    #pragma unroll
    for (int c = 0; c < 4; c++) {
        float4 tt = qp[c];
        qv[4*c+0]=tt.x; qv[4*c+1]=tt.y; qv[4*c+2]=tt.z; qv[4*c+3]=tt.w;
    }
    float ss = 0.f;
    #pragma unroll
    for (int j = 0; j < 16; j++) ss += qv[j] * qv[j];
    ss += __shfl_xor(ss, 1);
    ss += __shfl_xor(ss, 2);
    float nr = sqrtf(ss); if (nr < 1e-12f) nr = 1e-12f;
    float kscale = 0.125f / nr;
    f16x8 qh0, qh1, kh0, kh1;
    #pragma unroll
    for (int j = 0; j < 8; j++) {
        qh0[j] = (_Float16)qv[j];            qh1[j] = (_Float16)qv[8+j];
        kh0[j] = (_Float16)(qv[j] * kscale); kh1[j] = (_Float16)(qv[8+j] * kscale);
    }
    *(f16x8*)(qhf + off) = qh0; *(f16x8*)(qhf + off + 8) = qh1;
    *(f16x8*)(khf + off) = kh0; *(f16x8*)(khf + off + 8) = kh1;

    const float4* vp = (const float4*)(value + off);
    float vv[16];
    #pragma unroll
    for (int c = 0; c < 4; c++) {
        float4 tt = vp[c];
        vv[4*c+0]=tt.x; vv[4*c+1]=tt.y; vv[4*c+2]=tt.z; vv[4*c+3]=tt.w;
    }
    f16x8 vh0, vh1;
    #pragma unroll
    for (int j = 0; j < 8; j++) { vh0[j]=(_Float16)vv[j]; vh1[j]=(_Float16)vv[8+j]; }
    *(f16x8*)(vhf + off) = vh0; *(f16x8*)(vhf + off + 8) = vh1;
}

// K1: split-f16 MFMA hash; XCD-pinned b; flags small-margin rows.
__global__ __launch_bounds__(256, 4) void k_hash(const float* __restrict__ q,
                                                 const _Float16* __restrict__ rhi_g,
                                                 const _Float16* __restrict__ rlo_g,
                                                 int* __restrict__ h_ws,
                                                 int* __restrict__ fix_cnt,
                                                 int* __restrict__ fix_list) {
    __shared__ __align__(16) char smem[36864];
    _Float16* Rhi = (_Float16*)smem;            // [128][72]
    _Float16* Rlo = (_Float16*)(smem + 18432);  // [128][72]
    float*    Sc  = (float*)smem;               // overlay [64][133]

    int xcd = blockIdx.x & 7, slot = blockIdx.x >> 3;
    int b = xcd * 2 + (slot >> 6), chunk = slot & 63;
    int tid = threadIdx.x;
    int w = tid >> 6, lane = tid & 63, quad = lane >> 4, l15 = lane & 15;

    {   // stage R split halves
        int row = tid >> 1, dh = (tid & 1) * 32;
        const _Float16* sh = rhi_g + ((size_t)b * 128 + row) * 64 + dh;
        const _Float16* sl = rlo_g + ((size_t)b * 128 + row) * 64 + dh;
        #pragma unroll
        for (int g = 0; g < 4; g++) {
            *(f16x8*)&Rhi[row * 72 + dh + g * 8] = *(const f16x8*)(sh + g * 8);
            *(f16x8*)&Rlo[row * 72 + dh + g * 8] = *(const f16x8*)(sl + g * 8);
        }
    }

    int qrow = chunk * 64 + w * 16 + l15;
    const float* qp = q + ((size_t)(b * L_ + qrow)) * 64;
    f16x8 Ahi[2], Alo[2];
    #pragma unroll
    for (int kt = 0; kt < 2; kt++) {
        float4 t0 = *(const float4*)(qp + kt * 32 + quad * 8);
        float4 t1 = *(const float4*)(qp + kt * 32 + quad * 8 + 4);
        float fv[8] = {t0.x, t0.y, t0.z, t0.w, t1.x, t1.y, t1.z, t1.w};
        #pragma unroll
        for (int j = 0; j < 8; j++) {
            _Float16 hi = (_Float16)fv[j];
            Ahi[kt][j] = hi;
            Alo[kt][j] = (_Float16)(fv[j] - (float)hi);
        }
    }
    __syncthreads();

    f32x4 acc[8];
    #pragma unroll
    for (int jt = 0; jt < 8; jt++) acc[jt] = (f32x4){0.f, 0.f, 0.f, 0.f};
    #pragma unroll
    for (int jt = 0; jt < 8; jt++) {
        #pragma unroll
        for (int kt = 0; kt < 2; kt++) {
            f16x8 bh = *(const f16x8*)&Rhi[(jt * 16 + l15) * 72 + kt * 32 + quad * 8];
            f16x8 bl = *(const f16x8*)&Rlo[(jt * 16 + l15) * 72 + kt * 32 + quad * 8];
            acc[jt] = __builtin_amdgcn_mfma_f32_16x16x32_f16(Ahi[kt], bh, acc[jt], 0, 0, 0);
            acc[jt] = __builtin_amdgcn_mfma_f32_16x16x32_f16(Ahi[kt], bl, acc[jt], 0, 0, 0);
            acc[jt] = __builtin_amdgcn_mfma_f32_16x16x32_f16(Alo[kt], bh, acc[jt], 0, 0, 0);
        }
    }
    __syncthreads();

    #pragma unroll
    for (int jt = 0; jt < 8; jt++) {
        #pragma unroll
        for (int reg = 0; reg < 4; reg++)
            Sc[(w * 16 + quad * 4 + reg) * 133 + jt * 16 + l15] = acc[jt][reg];
    }
    __syncthreads();

    {
        int row = tid & 63, r = tid >> 6;
        const float* sp = &Sc[row * 133 + r * 32];
        float bp = -1e30f, bn = -1e30f; int ip = 0, in2 = 0;
        float v1 = -1e30f, v2 = -1e30f;
        #pragma unroll
        for (int n = 0; n < 32; n++) {
            float v = sp[n], nv = -v;
            if (v > bp)  { bp = v;  ip = n; }
            if (nv > bn) { bn = nv; in2 = n; }
            if (v > v1)       { v2 = v1; v1 = v; }
            else if (v > v2)  { v2 = v; }
            if (nv > v1)      { v2 = v1; v1 = nv; }
            else if (nv > v2) { v2 = nv; }
        }
        int i1 = (bp >= bn) ? ip : (32 + in2);
        int l = chunk * 64 + row;
        h_ws[((size_t)(b * 4 + r)) * L_ + l] = i1;
        if (v1 - v2 < 4e-5f) {
            int slot2 = atomicAdd(fix_cnt, 1);
            if (slot2 < FIXCAP) fix_list[slot2] = (b << 14) | (r << 12) | l;
        }
    }
}

// K2: stable counting sort per (b,r) with fused exact-fix prologue.
__global__ __launch_bounds__(256) void k_sort(const float* __restrict__ q,
                                              const double* __restrict__ rmn,
                                              const int* __restrict__ fix_cnt,
                                              const int* __restrict__ fix_list,
                                              int* __restrict__ h_ws,
                                              int* __restrict__ hi_ws,
                                              int* __restrict__ oi_ws) {
    __shared__ unsigned short hs16[4096];
    __shared__ unsigned short cnt[256 * 66];
    __shared__ int partial[4 * 64];
    __shared__ int baseb[64];
    int br = blockIdx.x;
    int* hp = h_ws + (size_t)br * L_;
    int t = threadIdx.x;
    int wave = t >> 6, lane = t & 63;
    for (int k = t; k < 4096; k += 256) hs16[k] = (unsigned short)hp[k];
    for (int k = t; k < 256 * 66; k += 256) cnt[k] = 0;
    __syncthreads();
    {   // fix prologue: resolve flagged rows of THIS br exactly (wave-parallel)
        int fcnt = *fix_cnt; if (fcnt > FIXCAP) fcnt = FIXCAP;
        int b = br >> 2;
        for (int i = wave; i < fcnt; i += 4) {
            int e = fix_list[i];
            if ((e >> 12) != br) continue;
            int l = e & 4095;
            int n = lane & 31;
            const double* rp = rmn + ((size_t)br) * 2048 + n * 64;
            const float* qr = q + ((size_t)(b * L_ + l)) * 64;
            double a0 = 0.0, a1 = 0.0, a2 = 0.0, a3 = 0.0;
            #pragma unroll
            for (int d = 0; d < 64; d += 4) {
                a0 += (double)qr[d]   * rp[d];
                a1 += (double)qr[d+1] * rp[d+1];
                a2 += (double)qr[d+2] * rp[d+2];
                a3 += (double)qr[d+3] * rp[d+3];
            }
            double acc = ((a0 + a1) + (a2 + a3));
            double v = (lane < 32) ? acc : -acc;
            int idx = lane;
            #pragma unroll
            for (int off = 1; off < 64; off <<= 1) {
                double ov = __shfl_xor(v, off);
                int   oidx = __shfl_xor(idx, off);
                if (ov > v || (ov == v && oidx < idx)) { v = ov; idx = oidx; }
            }
            if (lane == 0) {
                hs16[l] = (unsigned short)idx;
                hp[l] = idx;              // k_meta reads h_ws later
            }
        }
    }
    __syncthreads();
    {
        unsigned short* row = &cnt[t * 66];
        int base = t * 16;
        #pragma unroll
        for (int k = 0; k < 16; k++) row[hs16[base + k]]++;
    }
    __syncthreads();
    {
        int u = t & 63, g = t >> 6;
        int s = 0;
        for (int c = g * 64; c < g * 64 + 64; c++) s += cnt[c * 66 + u];
        partial[g * 64 + u] = s;
    }
    __syncthreads();
    if (t < 64) {
        int tot = partial[t] + partial[64 + t] + partial[128 + t] + partial[192 + t];
        int v = tot;
        #pragma unroll
        for (int off = 1; off < 64; off <<= 1) {
            int u2 = __shfl_up(v, off);
            if (t >= off) v += u2;
        }
        baseb[t] = v - tot;
    }
    __syncthreads();
    {
        int u = t & 63, g = t >> 6;
        int running = baseb[u];
        for (int gg = 0; gg < g; gg++) running += partial[gg * 64 + u];
        for (int c = g * 64; c < g * 64 + 64; c++) {
            int tmp = cnt[c * 66 + u];
            cnt[c * 66 + u] = (unsigned short)running;
            running += tmp;
        }
    }
    __syncthreads();
    {
        int* hi = hi_ws + (size_t)br * L_;
        int* oi = oi_ws + (size_t)br * L_;
        unsigned short* row = &cnt[t * 66];
        int base = t * 16;
        #pragma unroll
        for (int k = 0; k < 16; k++) {
            int idx = base + k;
            int bucket = hs16[idx];
            int pos = row[bucket]++;
            hi[pos] = idx;
            oi[idx] = pos;
        }
    }
}

// K2b: per sorted position meta record
__global__ __launch_bounds__(256) void k_meta(const int* __restrict__ h_ws,
                                              const int* __restrict__ hi_ws,
                                              const int* __restrict__ oi_ws,
                                              int4* __restrict__ meta_ws) {
    int gid = blockIdx.x * 256 + threadIdx.x;
    int br = gid >> 12, spos = gid & 4095;
    int b = br >> 2;
    int p = hi_ws[(size_t)br * L_ + spos];
    int hh = h_ws[(size_t)br * L_ + p];
    int pack = 0, packm1 = 0;
    #pragma unroll
    for (int r2 = 0; r2 < 4; r2++) {
        int bk = oi_ws[((size_t)(b * 4 + r2)) * L_ + p] >> 6;
        pack   |= bk << (8 * r2);
        packm1 |= ((bk + 63) & 63) << (8 * r2);
    }
    meta_ws[(size_t)br * L_ + spos] = make_int4(hh, p, pack, packm1);
}

// K3: MFMA fused attention, single 4096-block dispatch (>=4 generations/CU).
// K staged in LDS (stride 76); Vt conflict-free; Ph overlays Ksh; XCD-pinned.
__global__ __launch_bounds__(256, 4) void k_attn(const _Float16* __restrict__ qhf,
                                                 const _Float16* __restrict__ khf,
                                                 const _Float16* __restrict__ vhf,
                                                 const int4* __restrict__ meta_ws,
                                                 float* __restrict__ lse_ws,
                                                 _Float16* __restrict__ attn_ws) {
    __shared__ _Float16 Ksh[128 * 76];    // 19456 B; overlaid by Ph[64][136]
    __shared__ _Float16 Vt[64 * 136];     // 17408 B
    __shared__ int4 kmeta[128];

    int xcd = blockIdx.x & 7, slot = blockIdx.x >> 3;
    int b = xcd * 2 + (slot >> 8);
    int rem = slot & 255, n = rem >> 2, r = rem & 3;
    int tid = threadIdx.x;
    int w = tid >> 6, lane = tid & 63, quad = lane >> 4, l15 = lane & 15;
    int hibase = (b * 4 + r) * L_;

    if (tid < 128) {
        int nprev = (n + 63) & 63;
        int spos = (tid < 64) ? (nprev * 64 + tid) : (n * 64 + (tid - 64));
        kmeta[tid] = meta_ws[hibase + spos];
    }
    __syncthreads();

    {   // stage K: pure gathered f16 copy, 2 threads per row
        int j = tid >> 1, dh = (tid & 1) * 32;
        const _Float16* src = khf + ((size_t)(b * L_ + kmeta[j].y)) * 64 + dh;
        #pragma unroll
        for (int g = 0; g < 4; g++)
            *(f16x8*)&Ksh[j * 76 + dh + g * 8] = *(const f16x8*)(src + g * 8);
    }
    {   // stage V^T: wave = d-quarter, lane = row-pair -> 2-way bank alias (free)
        int p0 = kmeta[2 * lane].y, p1 = kmeta[2 * lane + 1].y;
        const _Float16* v0 = vhf + ((size_t)(b * L_ + p0)) * 64 + w * 16;
        const _Float16* v1 = vhf + ((size_t)(b * L_ + p1)) * 64 + w * 16;
        f16x8 a00 = *(const f16x8*)v0, a01 = *(const f16x8*)(v0 + 8);
        f16x8 a10 = *(const f16x8*)v1, a11 = *(const f16x8*)(v1 + 8);
        #pragma unroll
        for (int d = 0; d < 8; d++) {
            f16x2 hv = { a00[d], a10[d] };
            *(f16x2*)&Vt[(w * 16 + d) * 136 + 2 * lane] = hv;
            f16x2 hw = { a01[d], a11[d] };
            *(f16x2*)&Vt[(w * 16 + 8 + d) * 136 + 2 * lane] = hw;
        }
    }

    int4 qmw = kmeta[64 + w * 16 + l15];
    const _Float16* qp = qhf + ((size_t)(b * L_ + qmw.y)) * 64;
    f16x8 afr[2];
    afr[0] = *(const f16x8*)(qp + quad * 8);
    afr[1] = *(const f16x8*)(qp + 32 + quad * 8);
    __syncthreads();

    f32x4 acc[8];
    #pragma unroll
    for (int jt = 0; jt < 8; jt++) acc[jt] = (f32x4){0.f, 0.f, 0.f, 0.f};
    #pragma unroll
    for (int jt = 0; jt < 8; jt++) {
        #pragma unroll
        for (int kt = 0; kt < 2; kt++) {
            f16x8 bfr = *(const f16x8*)&Ksh[(jt * 16 + l15) * 76 + kt * 32 + quad * 8];
            acc[jt] = __builtin_amdgcn_mfma_f32_16x16x32_f16(afr[kt], bfr, acc[jt], 0, 0, 0);
        }
    }

    int4 qm4[4], km4[8];
    #pragma unroll
    for (int reg = 0; reg < 4; reg++) qm4[reg] = kmeta[64 + w * 16 + quad * 4 + reg];
    #pragma unroll
    for (int jt = 0; jt < 8; jt++) km4[jt] = kmeta[jt * 16 + l15];
    __syncthreads();                      // QK reads of Ksh done -> overlay

    _Float16* Ph = Ksh;                   // [64][136]
    float lse_r[4];
    #pragma unroll
    for (int reg = 0; reg < 4; reg++) {
        float s[8];
        #pragma unroll
        for (int jt = 0; jt < 8; jt++) {
            float v = acc[jt][reg];
            if (km4[jt].x != qm4[reg].x) v = -1e9f;
            if (qm4[reg].y < km4[jt].y)  v = -1e9f;
            if (qm4[reg].y == km4[jt].y) v = -1e5f;
            s[jt] = v;
        }
        float m = s[0];
        #pragma unroll
        for (int jt = 1; jt < 8; jt++) m = fmaxf(m, s[jt]);
        #pragma unroll
        for (int off = 1; off < 16; off <<= 1) m = fmaxf(m, __shfl_xor(m, off));
        float te[8], sum = 0.f;
        #pragma unroll
        for (int jt = 0; jt < 8; jt++) { te[jt] = __expf(s[jt] - m); sum += te[jt]; }
        #pragma unroll
        for (int off = 1; off < 16; off <<= 1) sum += __shfl_xor(sum, off);
        float inv = __builtin_amdgcn_rcpf(sum);
        lse_r[reg] = m + __logf(sum);
        int i = w * 16 + quad * 4 + reg;
        #pragma unroll
        for (int jt = 0; jt < 8; jt++) {
            int z1 = km4[jt].z ^ qm4[reg].z;
            int z2 = km4[jt].z ^ qm4[reg].w;
            int nz = __popc((z1 + 0x7f7f7f7f) & 0x80808080)
                   + __popc((z2 + 0x7f7f7f7f) & 0x80808080);
            float p = te[jt] * inv * __builtin_amdgcn_rcpf((float)(8 - nz));
            Ph[i * 136 + jt * 16 + l15] = (_Float16)p;
        }
    }
    if (l15 == 0) {
        #pragma unroll
        for (int reg = 0; reg < 4; reg++)
            lse_ws[hibase + qm4[reg].y] = lse_r[reg];
    }
    __syncthreads();                      // Ph complete

    f32x4 oacc[4];
    #pragma unroll
    for (int nt = 0; nt < 4; nt++) oacc[nt] = (f32x4){0.f, 0.f, 0.f, 0.f};
    #pragma unroll
    for (int kt = 0; kt < 4; kt++) {
        f16x8 pa = *(const f16x8*)&Ph[(w * 16 + l15) * 136 + kt * 32 + quad * 8];
        #pragma unroll
        for (int nt = 0; nt < 4; nt++) {
            f16x8 vb = *(const f16x8*)&Vt[(nt * 16 + l15) * 136 + kt * 32 + quad * 8];
            oacc[nt] = __builtin_amdgcn_mfma_f32_16x16x32_f16(pa, vb, oacc[nt], 0, 0, 0);
        }
    }
    #pragma unroll
    for (int reg = 0; reg < 4; reg++) {
        size_t base = (((size_t)(b * L_ + qm4[reg].y)) * 4 + r) * 64;
        #pragma unroll
        for (int nt = 0; nt < 4; nt++)
            attn_ws[base + nt * 16 + l15] = (_Float16)oacc[nt][reg];
    }
}

// K4a: per (b,r) softmax-over-L stats of lse
__global__ __launch_bounds__(256) void k_rw(const float* __restrict__ lse_ws,
                                            float* __restrict__ rwmax,
                                            float* __restrict__ rwsum) {
    __shared__ float  red[256];
    __shared__ double redd[256];
    int br = blockIdx.x;
    const float* lp = lse_ws + (size_t)br * L_;
    int t = threadIdx.x;
    float m = -1e30f;
    for (int k = t; k < L_; k += 256) m = fmaxf(m, lp[k]);
    red[t] = m; __syncthreads();
    for (int s2 = 128; s2 > 0; s2 >>= 1) {
        if (t < s2) red[t] = fmaxf(red[t], red[t + s2]);
        __syncthreads();
    }
    float mm = red[0];
    double s = 0.0;
    for (int k = t; k < L_; k += 256) s += (double)expf(lp[k] - mm);
    redd[t] = s; __syncthreads();
    for (int s2 = 128; s2 > 0; s2 >>= 1) {
        if (t < s2) redd[t] += redd[t + s2];
        __syncthreads();
    }
    if (t == 0) { rwmax[br] = mm; rwsum[br] = (float)redd[0]; }
}

// K4b: combine. XCD-pinned b; attn [B][L][R][64] -> 512 B contiguous per row.
__global__ __launch_bounds__(256) void k_out(const _Float16* __restrict__ attn_ws,
                                             const float* __restrict__ lse_ws,
                                             const float* __restrict__ rwmax,
                                             const float* __restrict__ rwsum,
                                             float* __restrict__ out) {
    int xcd = blockIdx.x & 7, slot = blockIdx.x >> 3;
    int b = xcd * 2 + (slot >> 7);
    int inner = slot & 127;
    int tid = threadIdx.x;
    int l = inner * 32 + (tid >> 3), g = tid & 7;
    size_t row = (size_t)b * L_ + l;
    float o[8];
    #pragma unroll
    for (int k = 0; k < 8; k++) o[k] = 0.f;
    #pragma unroll
    for (int r = 0; r < 4; r++) {
        int br = b * 4 + r;
        float wgt = __expf(lse_ws[(size_t)br * L_ + l] - rwmax[br])
                  * __builtin_amdgcn_rcpf(rwsum[br]);
        f16x8 av = *(const f16x8*)&attn_ws[(row * 4 + r) * 64 + g * 8];
        #pragma unroll
        for (int k = 0; k < 8; k++) o[k] += (float)av[k] * wgt;
    }
    float4* op = (float4*)(out + row * 64 + g * 8);
    op[0] = make_float4(o[0], o[1], o[2], o[3]);
    op[1] = make_float4(o[4], o[5], o[6], o[7]);
}

extern "C" void kernel_launch(void* const* d_in, const int* in_sizes, int n_in,
                              void* d_out, int out_size, void* d_ws, size_t ws_size,
                              hipStream_t stream) {
    const float* query = (const float*)d_in[0];
    const float* value = (const float*)d_in[1];
    const float* rm    = (const float*)d_in[2];
    char* ws = (char*)d_ws;
    double*    rmn    = (double*)ws;
    int*       h_ws   = (int*)(ws + ((size_t)1 << 20));
    int*       hi_ws  = (int*)(ws + ((size_t)2 << 20));
    int*       oi_ws  = (int*)(ws + ((size_t)3 << 20));
    float*     lse_ws = (float*)(ws + ((size_t)4 << 20));
    float*     rwmax  = (float*)(ws + ((size_t)5 << 20));
    float*     rwsum  = (float*)(ws + ((size_t)5 << 20) + 256);
    int*       fix_cnt= (int*)(ws + ((size_t)5 << 20) + 512);
    int*       fix_list=(int*)(ws + ((size_t)5 << 20) + 1024);
    _Float16*  attn_ws= (_Float16*)(ws + ((size_t)6 << 20));
    _Float16*  rhi_g  = (_Float16*)(ws + ((size_t)40 << 20));
    _Float16*  rlo_g  = (_Float16*)(ws + ((size_t)40 << 20) + ((size_t)1 << 19));
    int4*      meta_ws= (int4*)(ws + ((size_t)41 << 20));
    _Float16*  qhf    = (_Float16*)(ws + ((size_t)45 << 20));
    _Float16*  khf    = (_Float16*)(ws + ((size_t)53 << 20));
    _Float16*  vhf    = (_Float16*)(ws + ((size_t)61 << 20));
    float*     out    = (float*)d_out;

    hipLaunchKernelGGL(k_init,   dim3(1536), dim3(256), 0, stream,
                       rm, query, value, rmn, rhi_g, rlo_g, qhf, khf, vhf, fix_cnt);
    hipLaunchKernelGGL(k_hash,   dim3(1024), dim3(256), 0, stream, query, rhi_g, rlo_g,
                       h_ws, fix_cnt, fix_list);
    hipLaunchKernelGGL(k_sort,   dim3(64),   dim3(256), 0, stream, query, rmn,
                       fix_cnt, fix_list, h_ws, hi_ws, oi_ws);
    hipLaunchKernelGGL(k_meta,   dim3(1024), dim3(256), 0, stream, h_ws, hi_ws, oi_ws, meta_ws);
    hipLaunchKernelGGL(k_attn,   dim3(4096), dim3(256), 0, stream,
                       qhf, khf, vhf, meta_ws, lse_ws, attn_ws);
    hipLaunchKernelGGL(k_rw,     dim3(64),   dim3(256), 0, stream, lse_ws, rwmax, rwsum);
    hipLaunchKernelGGL(k_out,    dim3(2048), dim3(256), 0, stream,
                       attn_ws, lse_ws, rwmax, rwsum, out);
}